// Round 6
// baseline (95.692 us; speedup 1.0000x reference)
//
#include <hip/hip_runtime.h>
#include <hip/hip_cooperative_groups.h>

namespace cg = cooperative_groups;

constexpr int B_   = 4;
constexpr int NL   = 8192;
constexpr int NH   = 2048;
constexpr int CH   = 256;
constexpr int CL   = 128;
constexpr int CIN  = 384;
constexpr int COUT = 256;

typedef _Float16 f16;
typedef _Float16 f16x8 __attribute__((ext_vector_type(8)));
typedef float    f32x4 __attribute__((ext_vector_type(4)));

// Branchless top-3 insert (strict < == earliest-index-wins on ties).
#define BINS(d, h, B0, B1, B2, I0, I1, I2) do {                              \
    bool m2_ = (d) < (B2); B2 = m2_ ? (d) : B2; I2 = m2_ ? (h) : I2;         \
    bool m1_ = (B2) < (B1);                                                  \
    { float t_ = B1; int ti_ = I1;                                           \
      B1 = m1_ ? B2 : B1; I1 = m1_ ? I2 : I1;                                \
      B2 = m1_ ? t_ : B2; I2 = m1_ ? ti_ : I2; }                             \
    bool m0_ = (B1) < (B0);                                                  \
    { float t_ = B0; int ti_ = I0;                                           \
      B0 = m0_ ? B1 : B0; I0 = m0_ ? I1 : I0;                                \
      B1 = m0_ ? t_ : B1; I1 = m0_ ? ti_ : I1; }                             \
} while (0)

// LDS map (51712 B total; regions alias across dead phases):
//   As   [0, 50176)       GEMM A-tile [64][392] f16
//   idxL [50176, 50944)   knn results int[3][64]   (live into GEMM prologue)
//   wL   [50944, 51712)   knn results float[3][64] (live into GEMM prologue)
//   tt   [0, 4224)        prep transpose tile   (dead before pts)
//   pts  [0, 32768)       knn high-point cache  (dead before As)
//   mdm  [32768, 36096)   knn merge dists       (dead before As)
//   mim  [36096, 37760)   knn merge idx         (dead before As)
//   red  [0, 32)          stats reduce buffer   (after GEMM)
//   Ys   [0, 36864)       fallback y-store tile (after GEMM)
#define SM_BYTES 51712

// ---------------------------------------------------------------------------
__device__ inline void dev_prep(int bid, int tid,
    const float* __restrict__ feat_high, const float* __restrict__ Wm,
    f16* __restrict__ fhT, f16* __restrict__ Wh, char* smraw)
{
    float (*tt)[33] = (float(*)[33])smraw;
    const int tx = tid & 31, ty = tid >> 5;
    #pragma unroll
    for (int k = 0; k < 4; ++k) {
        const int u  = bid * 4 + k;            // 2048 tiles total
        const int ub = u >> 9, ut = u & 511;
        const int h0 = (ut & 63) * 32, c0 = (ut >> 6) * 32;
        #pragma unroll
        for (int pp = 0; pp < 4; ++pp)
            tt[ty + pp * 8][tx] =
                feat_high[((size_t)ub * CH + c0 + ty + pp * 8) * NH + h0 + tx];
        __syncthreads();
        #pragma unroll
        for (int pp = 0; pp < 4; ++pp)
            fhT[((size_t)ub * NH + h0 + ty + pp * 8) * CH + c0 + tx] =
                (f16)tt[tx][ty + pp * 8];
        __syncthreads();
    }
    if (bid < 384) Wh[bid * 256 + tid] = (f16)Wm[bid * 256 + tid];
}

// ---------------------------------------------------------------------------
// Block-local 3-NN for this block's 64 low points. Wave w scans NH-slice
// [w*512, w*512+512): pts[h] is wave-uniform (LDS broadcast, conflict-free).
// Results land in idxL/wL (LDS). Ends with __syncthreads.
// ---------------------------------------------------------------------------
__device__ inline void dev_knn(int b, int l0, int tid,
    const float* __restrict__ xyz_low, const float* __restrict__ xyz_high,
    char* smraw)
{
    float4* pts  = (float4*)smraw;
    float*  mdm  = (float*)(smraw + 32768);
    short*  mim  = (short*)(smraw + 36096);
    int*    idxL = (int*)(smraw + 50176);
    float*  wL   = (float*)(smraw + 50944);
    const int w = tid >> 6, p = tid & 63;

    const float* xh = xyz_high + (size_t)b * NH * 3;
    for (int h = tid; h < NH; h += 256) {
        float x = xh[h * 3], yy = xh[h * 3 + 1], z = xh[h * 3 + 2];
        pts[h] = make_float4(x, yy, z, x * x + yy * yy + z * z);
    }
    __syncthreads();

    const float* xl = xyz_low + ((size_t)b * NL + l0 + p) * 3;
    const float lx = xl[0], ly = xl[1], lz = xl[2];
    const float sl = lx * lx + ly * ly + lz * lz;

    float b0 = 1e30f, b1 = 1e30f, b2 = 1e30f;
    int i0 = 0, i1 = 0, i2 = 0;
    const int h0 = w * 512;
    #pragma unroll 4
    for (int h = h0; h < h0 + 512; ++h) {
        float4 pt = pts[h];
        float d2 = fmaf(-2.0f, fmaf(lx, pt.x, fmaf(ly, pt.y, lz * pt.z)),
                        sl + pt.w);
        BINS(d2, h, b0, b1, b2, i0, i1, i2);
    }
    // mdm/mim [32768,37760) does not alias pts [0,32768): no barrier needed
    const int cb = p * 13 + w * 3;
    mdm[cb] = b0;     mim[cb] = (short)i0;
    mdm[cb + 1] = b1; mim[cb + 1] = (short)i1;
    mdm[cb + 2] = b2; mim[cb + 2] = (short)i2;
    __syncthreads();

    if (tid < 64) {   // merge 12 candidates in slice order (tie-stable)
        float e0 = 1e30f, e1 = 1e30f, e2 = 1e30f;
        int j0 = 0, j1 = 0, j2 = 0;
        #pragma unroll
        for (int q = 0; q < 12; ++q) {
            float d = mdm[tid * 13 + q];
            int  ii = mim[tid * 13 + q];
            BINS(d, ii, e0, e1, e2, j0, j1, j2);
        }
        float d0 = sqrtf(fmaxf(e0, 0.0f));
        float d1 = sqrtf(fmaxf(e1, 0.0f));
        float d2f = sqrtf(fmaxf(e2, 0.0f));
        float iw0 = 1.0f / fmaxf(d0, 1e-8f);
        float iw1 = 1.0f / fmaxf(d1, 1e-8f);
        float iw2 = 1.0f / fmaxf(d2f, 1e-8f);
        float sum = iw0 + iw1 + iw2;
        idxL[tid] = j0; idxL[64 + tid] = j1; idxL[128 + tid] = j2;
        wL[tid] = iw0 / sum; wL[64 + tid] = iw1 / sum; wL[128 + tid] = iw2 / sum;
    }
    __syncthreads();
}

// ---------------------------------------------------------------------------
// interp gather -> As, then barrier-free K-loop: A-frags (W) straight from
// global (L2-hot, 192 KB shared by all blocks), B-frags from LDS As.
// Epilogue: bias into acc + per-block BN partials. Ends with __syncthreads.
// ---------------------------------------------------------------------------
__device__ inline void dev_gemm(int b, int l0, int bid, int tid,
    const f16* __restrict__ fhT, const float* __restrict__ feat_low,
    const f16* __restrict__ Wh, const float* __restrict__ bias,
    char* smraw, f32x4 acc[4][4],
    float* __restrict__ ps, float* __restrict__ psq)
{
    f16*   As   = (f16*)smraw;
    int*   idxL = (int*)(smraw + 50176);
    float* wL   = (float*)(smraw + 50944);
    const int lane = tid & 63, w = tid >> 6;

    {   // prologue: interp gather (k<256) + feat_low direct staging (k>=256)
        const int p = tid >> 2, q = tid & 3;
        const int j0 = idxL[p], j1 = idxL[64 + p], j2 = idxL[128 + p];
        const float u0 = wL[p], u1 = wL[64 + p], u2 = wL[128 + p];
        const f16* r0 = fhT + ((size_t)b * NH + j0) * CH + q * 64;
        const f16* r1 = fhT + ((size_t)b * NH + j1) * CH + q * 64;
        const f16* r2 = fhT + ((size_t)b * NH + j2) * CH + q * 64;
        #pragma unroll
        for (int j = 0; j < 8; ++j) {
            f16x8 v0 = *(const f16x8*)(r0 + j * 8);
            f16x8 v1 = *(const f16x8*)(r1 + j * 8);
            f16x8 v2 = *(const f16x8*)(r2 + j * 8);
            f16x8 o;
            #pragma unroll
            for (int e = 0; e < 8; ++e)
                o[e] = (f16)(u0 * (float)v0[e] + u1 * (float)v1[e]
                             + u2 * (float)v2[e]);
            *(f16x8*)&As[p * 392 + q * 64 + j * 8] = o;
        }
        const float* flb = feat_low + ((size_t)b * CL + q * 32) * NL + l0 + p;
        f16 tmp[32];
        #pragma unroll
        for (int i = 0; i < 32; ++i)
            tmp[i] = (f16)flb[(size_t)i * NL];
        #pragma unroll
        for (int j = 0; j < 4; ++j)
            *(f16x8*)&As[p * 392 + 256 + q * 32 + j * 8] =
                *(const f16x8*)&tmp[j * 8];
    }
    __syncthreads();

    const int kb = (lane >> 4) * 8;
    const int r  = lane & 15;
    #pragma unroll
    for (int kt = 0; kt < 12; ++kt) {
        const int k0 = kt * 32;
        f16x8 a[4], bb[4];
        #pragma unroll
        for (int mi = 0; mi < 4; ++mi)
            a[mi] = *(const f16x8*)&Wh[(size_t)(w * 64 + mi * 16 + r) * CIN
                                       + k0 + kb];
        #pragma unroll
        for (int ni = 0; ni < 4; ++ni)
            bb[ni] = *(const f16x8*)&As[(ni * 16 + r) * 392 + k0 + kb];
        #pragma unroll
        for (int mi = 0; mi < 4; ++mi)
            #pragma unroll
            for (int ni = 0; ni < 4; ++ni)
                acc[mi][ni] = __builtin_amdgcn_mfma_f32_16x16x32_f16(
                    a[mi], bb[ni], acc[mi][ni], 0, 0, 0);
    }

    const int r4 = (lane >> 4) * 4, cl = lane & 15;
    #pragma unroll
    for (int mi = 0; mi < 4; ++mi) {
        #pragma unroll
        for (int j = 0; j < 4; ++j) {
            const int o = w * 64 + mi * 16 + r4 + j;
            const float bi = bias[o];
            float s = 0.0f, sq = 0.0f;
            #pragma unroll
            for (int ni = 0; ni < 4; ++ni) {
                acc[mi][ni][j] += bi;
                float v = acc[mi][ni][j];
                s += v; sq += v * v;
            }
            #pragma unroll
            for (int m = 1; m < 16; m <<= 1) {
                s  += __shfl_xor(s, m);
                sq += __shfl_xor(sq, m);
            }
            if (cl == 0) {
                ps [o * 512 + bid] = s;
                psq[o * 512 + bid] = sq;
            }
        }
    }
    __syncthreads();   // all As reads done -> safe to alias (red/Ys)
}

// ---------------------------------------------------------------------------
__device__ inline void dev_stats(int o, int tid,
    const float* __restrict__ ps, const float* __restrict__ psq,
    float* __restrict__ mean, float* __restrict__ rstd, float* red)
{
    float s = ps[o * 512 + tid] + ps[o * 512 + 256 + tid];
    float q = psq[o * 512 + tid] + psq[o * 512 + 256 + tid];
    #pragma unroll
    for (int m = 32; m > 0; m >>= 1) {
        s += __shfl_down(s, m);
        q += __shfl_down(q, m);
    }
    const int w = tid >> 6, lane = tid & 63;
    if (lane == 0) { red[w] = s; red[4 + w] = q; }
    __syncthreads();
    if (tid == 0) {
        s = red[0] + red[1] + red[2] + red[3];
        q = red[4] + red[5] + red[6] + red[7];
        const float n = (float)(B_ * NL);
        const float m = s / n;
        mean[o] = m;
        rstd[o] = rsqrtf(q / n - m * m + 1e-5f);
    }
}

// ---------------------------------------------------------------------------
// PRIMARY: one cooperative kernel (512 blocks x 256 thr, 51.7 KB LDS).
// ---------------------------------------------------------------------------
__global__ __launch_bounds__(256, 2) void fused_kernel(
    const float* __restrict__ xyz_low, const float* __restrict__ xyz_high,
    const float* __restrict__ feat_low, const float* __restrict__ feat_high,
    const float* __restrict__ Wm, const float* __restrict__ bias,
    const float* __restrict__ gamma, const float* __restrict__ beta,
    f16* __restrict__ fhT, f16* __restrict__ Wh,
    float* __restrict__ ps, float* __restrict__ psq,
    float* __restrict__ mean, float* __restrict__ rstd,
    float* __restrict__ y)
{
    __shared__ __align__(16) char smraw[SM_BYTES];
    cg::grid_group grid = cg::this_grid();
    const int bid = blockIdx.x, tid = threadIdx.x;
    const int b = bid >> 7, l0 = (bid & 127) * 64;

    dev_prep(bid, tid, feat_high, Wm, fhT, Wh, smraw);
    dev_knn(b, l0, tid, xyz_low, xyz_high, smraw);

    __threadfence();
    grid.sync();   // fhT / Wh visible device-wide

    f32x4 acc[4][4] = {};
    dev_gemm(b, l0, bid, tid, fhT, feat_low, Wh, bias, smraw, acc, ps, psq);

    __threadfence();
    grid.sync();   // all partials visible

    if (bid < 256)
        dev_stats(bid, tid, ps, psq, mean, rstd, (float*)smraw);

    __threadfence();
    grid.sync();   // mean/rstd visible

    const int lane = tid & 63, w = tid >> 6;
    const int r4 = (lane >> 4) * 4, cl = lane & 15;
    #pragma unroll
    for (int mi = 0; mi < 4; ++mi) {
        #pragma unroll
        for (int j = 0; j < 4; ++j) {
            const int o = w * 64 + mi * 16 + r4 + j;
            const float m = mean[o], rs = rstd[o];
            const float g = gamma[o], be = beta[o];
            float* dst = &y[((size_t)b * COUT + o) * NL + l0 + cl];
            #pragma unroll
            for (int ni = 0; ni < 4; ++ni) {
                float v = acc[mi][ni][j];
                dst[ni * 16] = fmaxf(fmaf(g, (v - m) * rs, be), 0.0f);
            }
        }
    }
}

// ---------------------------------------------------------------------------
// FALLBACK pipeline (engaged only if coop co-residency is rejected).
// ---------------------------------------------------------------------------
__global__ __launch_bounds__(256, 2) void knn_fb_kernel(
    const float* __restrict__ xyz_low, const float* __restrict__ xyz_high,
    const float* __restrict__ feat_high, const float* __restrict__ Wm,
    f16* __restrict__ fhT, f16* __restrict__ Wh,
    int* __restrict__ idxG, float* __restrict__ wG)
{
    __shared__ __align__(16) char smraw[SM_BYTES];
    const int bid = blockIdx.x, tid = threadIdx.x;
    const int b = bid >> 7, l0 = (bid & 127) * 64;
    dev_prep(bid, tid, feat_high, Wm, fhT, Wh, smraw);
    dev_knn(b, l0, tid, xyz_low, xyz_high, smraw);
    int*   idxL = (int*)(smraw + 50176);
    float* wL   = (float*)(smraw + 50944);
    if (tid < 192) {
        idxG[bid * 192 + tid] = idxL[tid];
        wG [bid * 192 + tid] = wL[tid];
    }
}

__global__ __launch_bounds__(256, 2) void gemm_fb_kernel(
    const float* __restrict__ feat_low, const f16* __restrict__ fhT,
    const f16* __restrict__ Wh, const float* __restrict__ bias,
    const int* __restrict__ idxG, const float* __restrict__ wG,
    f16* __restrict__ yh, float* __restrict__ ps, float* __restrict__ psq)
{
    __shared__ __align__(16) char smraw[SM_BYTES];
    const int bid = blockIdx.x, tid = threadIdx.x;
    const int b = bid >> 7, l0 = (bid & 127) * 64;
    int*   idxL = (int*)(smraw + 50176);
    float* wL   = (float*)(smraw + 50944);
    if (tid < 192) {
        idxL[tid] = idxG[bid * 192 + tid];
        wL[tid]   = wG [bid * 192 + tid];
    }
    __syncthreads();

    f32x4 acc[4][4] = {};
    dev_gemm(b, l0, bid, tid, fhT, feat_low, Wh, bias, smraw, acc, ps, psq);

    f16* Ys = (f16*)smraw;             // [256][72], aliases As (dead)
    const int lane = tid & 63, w = tid >> 6;
    const int r4 = (lane >> 4) * 4, cl = lane & 15;
    #pragma unroll
    for (int mi = 0; mi < 4; ++mi)
        #pragma unroll
        for (int j = 0; j < 4; ++j) {
            const int o = w * 64 + mi * 16 + r4 + j;
            #pragma unroll
            for (int ni = 0; ni < 4; ++ni)
                Ys[o * 72 + cl + ni * 16] = (f16)acc[mi][ni][j];
        }
    __syncthreads();
    const int q = tid & 3;
    #pragma unroll
    for (int rep = 0; rep < 4; ++rep) {
        const int o = rep * 64 + (tid >> 2);
        f16* dst = yh + ((size_t)b * COUT + o) * NL + l0 + q * 16;
        *(f16x8*)(dst)     = *(const f16x8*)&Ys[o * 72 + q * 16];
        *(f16x8*)(dst + 8) = *(const f16x8*)&Ys[o * 72 + q * 16 + 8];
    }
}

__global__ __launch_bounds__(256) void bn_stats_fb(
    const float* __restrict__ ps, const float* __restrict__ psq,
    float* __restrict__ mean, float* __restrict__ rstd)
{
    __shared__ float red[8];
    dev_stats(blockIdx.x, threadIdx.x, ps, psq, mean, rstd, red);
}

__global__ __launch_bounds__(256) void bn_apply_fb(
    const f16* __restrict__ yh, float* __restrict__ y,
    const float* __restrict__ mean, const float* __restrict__ rstd,
    const float* __restrict__ gamma, const float* __restrict__ beta)
{
    const size_t e8 = (size_t)blockIdx.x * 256 + threadIdx.x;
    const int oc = (int)((e8 >> 10) & (COUT - 1));
    f16x8 v = ((const f16x8*)yh)[e8];
    const float m = mean[oc], rs = rstd[oc], g = gamma[oc], be = beta[oc];
    float4 o1, o2;
    o1.x = fmaxf(fmaf(g, ((float)v[0] - m) * rs, be), 0.0f);
    o1.y = fmaxf(fmaf(g, ((float)v[1] - m) * rs, be), 0.0f);
    o1.z = fmaxf(fmaf(g, ((float)v[2] - m) * rs, be), 0.0f);
    o1.w = fmaxf(fmaf(g, ((float)v[3] - m) * rs, be), 0.0f);
    o2.x = fmaxf(fmaf(g, ((float)v[4] - m) * rs, be), 0.0f);
    o2.y = fmaxf(fmaf(g, ((float)v[5] - m) * rs, be), 0.0f);
    o2.z = fmaxf(fmaf(g, ((float)v[6] - m) * rs, be), 0.0f);
    o2.w = fmaxf(fmaf(g, ((float)v[7] - m) * rs, be), 0.0f);
    ((float4*)y)[e8 * 2]     = o1;
    ((float4*)y)[e8 * 2 + 1] = o2;
}

// ---------------------------------------------------------------------------
extern "C" void kernel_launch(void* const* d_in, const int* in_sizes, int n_in,
                              void* d_out, int out_size, void* d_ws, size_t ws_size,
                              hipStream_t stream)
{
    const float* xyz_low   = (const float*)d_in[0];
    const float* xyz_high  = (const float*)d_in[1];
    const float* feat_low  = (const float*)d_in[2];
    const float* feat_high = (const float*)d_in[3];
    const float* Wm        = (const float*)d_in[4];
    const float* bias      = (const float*)d_in[5];
    const float* gamma     = (const float*)d_in[6];
    const float* beta      = (const float*)d_in[7];
    float* y = (float*)d_out;

    float* ps   = (float*)d_ws;                        // 256*512 f32
    float* psq  = ps + (size_t)COUT * 512;             // 256*512 f32
    float* mean = psq + (size_t)COUT * 512;            // 256
    float* rstd = mean + COUT;                         // 256 (+pad to 1024B)
    int*   idxG = (int*)(rstd + COUT + 256);           // 512*192 int
    float* wG   = (float*)(idxG + 512 * 192);          // 512*192 f32
    f16*   Wh   = (f16*)(wG + 512 * 192);              // 256*384 f16
    f16*   fhT  = Wh + (size_t)COUT * CIN;             // 4*2048*256 f16 (4.2MB)
    f16*   yh   = fhT + (size_t)B_ * NH * CH;          // 4*256*8192 f16 (16.8MB)

    int nb = 0;
    hipError_t qe = hipOccupancyMaxActiveBlocksPerMultiprocessor(
        &nb, (const void*)fused_kernel, 256, 0);

    if (qe == hipSuccess && nb >= 2) {
        void* args[] = {
            (void*)&xyz_low, (void*)&xyz_high, (void*)&feat_low,
            (void*)&feat_high, (void*)&Wm, (void*)&bias, (void*)&gamma,
            (void*)&beta, (void*)&fhT, (void*)&Wh, (void*)&ps, (void*)&psq,
            (void*)&mean, (void*)&rstd, (void*)&y
        };
        hipLaunchCooperativeKernel((const void*)fused_kernel, dim3(512),
                                   dim3(256), args, 0, stream);
    } else {
        knn_fb_kernel<<<512, 256, 0, stream>>>(
            xyz_low, xyz_high, feat_high, Wm, fhT, Wh, idxG, wG);
        gemm_fb_kernel<<<512, 256, 0, stream>>>(
            feat_low, fhT, Wh, bias, idxG, wG, yh, ps, psq);
        bn_stats_fb<<<COUT, 256, 0, stream>>>(ps, psq, mean, rstd);
        bn_apply_fb<<<(int)((size_t)B_ * COUT * NL / 8 / 256), 256, 0, stream>>>(
            yh, y, mean, rstd, gamma, beta);
    }
}

// Round 7
// 90.999 us; speedup vs baseline: 1.0516x; 1.0516x over previous
//
#include <hip/hip_runtime.h>

constexpr int B_   = 4;
constexpr int NL   = 8192;
constexpr int NH   = 2048;
constexpr int CH   = 256;
constexpr int CL   = 128;
constexpr int CIN  = 384;
constexpr int COUT = 256;

typedef _Float16 f16;
typedef _Float16 f16x8 __attribute__((ext_vector_type(8)));
typedef float    f32x4 __attribute__((ext_vector_type(4)));

// Branchless top-3 insert (strict < == earliest-index-wins on ties).
#define BINS(d, h, B0, B1, B2, I0, I1, I2) do {                              \
    bool m2_ = (d) < (B2); B2 = m2_ ? (d) : B2; I2 = m2_ ? (h) : I2;         \
    bool m1_ = (B2) < (B1);                                                  \
    { float t_ = B1; int ti_ = I1;                                           \
      B1 = m1_ ? B2 : B1; I1 = m1_ ? I2 : I1;                                \
      B2 = m1_ ? t_ : B2; I2 = m1_ ? ti_ : I2; }                             \
    bool m0_ = (B1) < (B0);                                                  \
    { float t_ = B0; int ti_ = I0;                                           \
      B0 = m0_ ? B1 : B0; I0 = m0_ ? I1 : I0;                                \
      B1 = m0_ ? t_ : B1; I1 = m0_ ? ti_ : I1; }                             \
} while (0)

// ---------------------------------------------------------------------------
// K1: role-fused. blocks [0,512): 3-NN (VALU-bound). [512,1024): fhT
// transpose (memory-bound). [1024,1408): W f32->f16. knn blocks first so
// the long pole dispatches earliest; transposes backfill idle pipes.
// knn: wave w scans NH-slice [w*512,w*512+512) for the block's 64 low pts;
// pts[h] is wave-uniform (LDS broadcast, conflict-free); merge arrays
// stride 13 (coprime 32). Results written straight to idxG/wG.
// ---------------------------------------------------------------------------
__global__ __launch_bounds__(256) void knn_prep_kernel(
    const float* __restrict__ xyz_low, const float* __restrict__ xyz_high,
    const float* __restrict__ feat_high, const float* __restrict__ Wm,
    f16* __restrict__ fhT, f16* __restrict__ Wh,
    int* __restrict__ idxG, float* __restrict__ wG)
{
    __shared__ __align__(16) char smraw[37760];
    const int bid = blockIdx.x, tid = threadIdx.x;

    if (bid < 512) {
        float4* pts = (float4*)smraw;                  // [0, 32768)
        float*  mdm = (float*)(smraw + 32768);         // 64*13 f32
        short*  mim = (short*)(smraw + 36096);         // 64*13 i16
        const int b = bid >> 7, l0 = (bid & 127) * 64;
        const int w = tid >> 6, p = tid & 63;

        const float* xh = xyz_high + (size_t)b * NH * 3;
        for (int h = tid; h < NH; h += 256) {
            float x = xh[h * 3], yy = xh[h * 3 + 1], z = xh[h * 3 + 2];
            pts[h] = make_float4(x, yy, z, x * x + yy * yy + z * z);
        }
        __syncthreads();

        const float* xl = xyz_low + ((size_t)b * NL + l0 + p) * 3;
        const float lx = xl[0], ly = xl[1], lz = xl[2];
        const float sl = lx * lx + ly * ly + lz * lz;

        float b0 = 1e30f, b1 = 1e30f, b2 = 1e30f;
        int i0 = 0, i1 = 0, i2 = 0;
        const int h0 = w * 512;
        #pragma unroll 4
        for (int h = h0; h < h0 + 512; ++h) {
            float4 pt = pts[h];
            float d2 = fmaf(-2.0f, fmaf(lx, pt.x, fmaf(ly, pt.y, lz * pt.z)),
                            sl + pt.w);
            BINS(d2, h, b0, b1, b2, i0, i1, i2);
        }
        // mdm/mim [32768,37760) does not alias pts: no barrier needed here
        const int cb = p * 13 + w * 3;
        mdm[cb] = b0;     mim[cb] = (short)i0;
        mdm[cb + 1] = b1; mim[cb + 1] = (short)i1;
        mdm[cb + 2] = b2; mim[cb + 2] = (short)i2;
        __syncthreads();

        if (tid < 64) {   // merge 12 candidates in slice order (tie-stable)
            float e0 = 1e30f, e1 = 1e30f, e2 = 1e30f;
            int j0 = 0, j1 = 0, j2 = 0;
            #pragma unroll
            for (int q = 0; q < 12; ++q) {
                float d = mdm[tid * 13 + q];
                int  ii = mim[tid * 13 + q];
                BINS(d, ii, e0, e1, e2, j0, j1, j2);
            }
            float d0 = sqrtf(fmaxf(e0, 0.0f));
            float d1 = sqrtf(fmaxf(e1, 0.0f));
            float d2f = sqrtf(fmaxf(e2, 0.0f));
            float iw0 = 1.0f / fmaxf(d0, 1e-8f);
            float iw1 = 1.0f / fmaxf(d1, 1e-8f);
            float iw2 = 1.0f / fmaxf(d2f, 1e-8f);
            float sum = iw0 + iw1 + iw2;
            idxG[bid * 192 + tid]       = j0;
            idxG[bid * 192 + 64 + tid]  = j1;
            idxG[bid * 192 + 128 + tid] = j2;
            wG[bid * 192 + tid]       = iw0 / sum;
            wG[bid * 192 + 64 + tid]  = iw1 / sum;
            wG[bid * 192 + 128 + tid] = iw2 / sum;
        }
    } else if (bid < 1024) {
        float (*tt)[33] = (float(*)[33])smraw;
        const int tx = tid & 31, ty = tid >> 5;
        #pragma unroll
        for (int k = 0; k < 4; ++k) {
            const int u  = (bid - 512) * 4 + k;        // 2048 tiles total
            const int ub = u >> 9, ut = u & 511;
            const int h0 = (ut & 63) * 32, c0 = (ut >> 6) * 32;
            #pragma unroll
            for (int pp = 0; pp < 4; ++pp)
                tt[ty + pp * 8][tx] =
                    feat_high[((size_t)ub * CH + c0 + ty + pp * 8) * NH + h0 + tx];
            __syncthreads();
            #pragma unroll
            for (int pp = 0; pp < 4; ++pp)
                fhT[((size_t)ub * NH + h0 + ty + pp * 8) * CH + c0 + tx] =
                    (f16)tt[tx][ty + pp * 8];
            __syncthreads();
        }
    } else {
        const int i = (bid - 1024) * 256 + tid;        // 384 blocks
        Wh[i] = (f16)Wm[i];
    }
}

// ---------------------------------------------------------------------------
// K2: interp gather -> As, barrier-free K-loop (W A-frags straight from
// global, L2-hot 192 KB; B-frags from LDS As), bias into acc, per-block BN
// partials, fp16 y staged through LDS for coalesced stores.
// ---------------------------------------------------------------------------
__global__ __launch_bounds__(256, 2) void gemm_kernel(
    const float* __restrict__ feat_low, const f16* __restrict__ fhT,
    const f16* __restrict__ Wh, const float* __restrict__ bias,
    const int* __restrict__ idxG, const float* __restrict__ wG,
    f16* __restrict__ yh, float* __restrict__ ps, float* __restrict__ psq)
{
    // As [0,50176) = [64][392] f16 ; idxL [50176,50944) ; wL [50944,51712)
    __shared__ __align__(16) char smraw[51712];
    f16*   As   = (f16*)smraw;
    int*   idxL = (int*)(smraw + 50176);
    float* wL   = (float*)(smraw + 50944);

    const int bid = blockIdx.x, tid = threadIdx.x;
    const int b = bid >> 7, l0 = (bid & 127) * 64;
    const int lane = tid & 63, w = tid >> 6;

    if (tid < 192) {
        idxL[tid] = idxG[bid * 192 + tid];
        wL[tid]   = wG [bid * 192 + tid];
    }
    __syncthreads();

    {   // prologue: interp gather (k<256) + feat_low direct staging (k>=256)
        const int p = tid >> 2, q = tid & 3;
        const int j0 = idxL[p], j1 = idxL[64 + p], j2 = idxL[128 + p];
        const float u0 = wL[p], u1 = wL[64 + p], u2 = wL[128 + p];
        const f16* r0 = fhT + ((size_t)b * NH + j0) * CH + q * 64;
        const f16* r1 = fhT + ((size_t)b * NH + j1) * CH + q * 64;
        const f16* r2 = fhT + ((size_t)b * NH + j2) * CH + q * 64;
        #pragma unroll
        for (int j = 0; j < 8; ++j) {
            f16x8 v0 = *(const f16x8*)(r0 + j * 8);
            f16x8 v1 = *(const f16x8*)(r1 + j * 8);
            f16x8 v2 = *(const f16x8*)(r2 + j * 8);
            f16x8 o;
            #pragma unroll
            for (int e = 0; e < 8; ++e)
                o[e] = (f16)(u0 * (float)v0[e] + u1 * (float)v1[e]
                             + u2 * (float)v2[e]);
            *(f16x8*)&As[p * 392 + q * 64 + j * 8] = o;
        }
        const float* flb = feat_low + ((size_t)b * CL + q * 32) * NL + l0 + p;
        f16 tmp[32];
        #pragma unroll
        for (int i = 0; i < 32; ++i)
            tmp[i] = (f16)flb[(size_t)i * NL];
        #pragma unroll
        for (int j = 0; j < 4; ++j)
            *(f16x8*)&As[p * 392 + 256 + q * 32 + j * 8] =
                *(const f16x8*)&tmp[j * 8];
    }
    __syncthreads();

    f32x4 acc[4][4] = {};
    const int kb = (lane >> 4) * 8;
    const int r  = lane & 15;
    #pragma unroll
    for (int kt = 0; kt < 12; ++kt) {
        const int k0 = kt * 32;
        f16x8 a[4], bb[4];
        #pragma unroll
        for (int mi = 0; mi < 4; ++mi)
            a[mi] = *(const f16x8*)&Wh[(size_t)(w * 64 + mi * 16 + r) * CIN
                                       + k0 + kb];
        #pragma unroll
        for (int ni = 0; ni < 4; ++ni)
            bb[ni] = *(const f16x8*)&As[(ni * 16 + r) * 392 + k0 + kb];
        #pragma unroll
        for (int mi = 0; mi < 4; ++mi)
            #pragma unroll
            for (int ni = 0; ni < 4; ++ni)
                acc[mi][ni] = __builtin_amdgcn_mfma_f32_16x16x32_f16(
                    a[mi], bb[ni], acc[mi][ni], 0, 0, 0);
    }

    // bias into acc + per-block BN partials (no LDS touched)
    const int r4 = (lane >> 4) * 4, cl = lane & 15;
    #pragma unroll
    for (int mi = 0; mi < 4; ++mi) {
        #pragma unroll
        for (int j = 0; j < 4; ++j) {
            const int o = w * 64 + mi * 16 + r4 + j;
            const float bi = bias[o];
            float s = 0.0f, sq = 0.0f;
            #pragma unroll
            for (int ni = 0; ni < 4; ++ni) {
                acc[mi][ni][j] += bi;
                float v = acc[mi][ni][j];
                s += v; sq += v * v;
            }
            #pragma unroll
            for (int m = 1; m < 16; m <<= 1) {
                s  += __shfl_xor(s, m);
                sq += __shfl_xor(sq, m);
            }
            if (cl == 0) {
                ps [o * 512 + bid] = s;
                psq[o * 512 + bid] = sq;
            }
        }
    }
    __syncthreads();   // all As reads done -> safe to alias with Ys

    f16* Ys = (f16*)smraw;             // [256][72] f16 = 36864 B
    #pragma unroll
    for (int mi = 0; mi < 4; ++mi)
        #pragma unroll
        for (int j = 0; j < 4; ++j) {
            const int o = w * 64 + mi * 16 + r4 + j;
            #pragma unroll
            for (int ni = 0; ni < 4; ++ni)
                Ys[o * 72 + cl + ni * 16] = (f16)acc[mi][ni][j];
        }
    __syncthreads();
    const int q = tid & 3;
    #pragma unroll
    for (int rep = 0; rep < 4; ++rep) {
        const int o = rep * 64 + (tid >> 2);
        f16* dst = yh + ((size_t)b * COUT + o) * NL + l0 + q * 16;
        *(f16x8*)(dst)     = *(const f16x8*)&Ys[o * 72 + q * 16];
        *(f16x8*)(dst + 8) = *(const f16x8*)&Ys[o * 72 + q * 16 + 8];
    }
}

// ---------------------------------------------------------------------------
// K3: fused BN stats + apply + ReLU. Grid (COUT, B_): each block reduces its
// channel's 512 partials (deterministic, redundant across the 4 b-blocks of
// a channel -> identical results) then applies to its (b,o) row of 8192.
// ---------------------------------------------------------------------------
__global__ __launch_bounds__(256) void stats_apply_kernel(
    const float* __restrict__ ps, const float* __restrict__ psq,
    const f16* __restrict__ yh,
    const float* __restrict__ gamma, const float* __restrict__ beta,
    float* __restrict__ y)
{
    const int o = blockIdx.x, b = blockIdx.y, tid = threadIdx.x;
    const int w = tid >> 6, lane = tid & 63;

    float s = ps[o * 512 + tid] + ps[o * 512 + 256 + tid];
    float q = psq[o * 512 + tid] + psq[o * 512 + 256 + tid];
    #pragma unroll
    for (int m = 32; m > 0; m >>= 1) {
        s += __shfl_down(s, m);
        q += __shfl_down(q, m);
    }
    __shared__ float red[8];
    if (lane == 0) { red[w] = s; red[4 + w] = q; }
    __syncthreads();
    s = red[0] + red[1] + red[2] + red[3];
    q = red[4] + red[5] + red[6] + red[7];
    const float n  = (float)(B_ * NL);
    const float mu = s / n;
    const float rs = rsqrtf(q / n - mu * mu + 1e-5f);
    const float g  = gamma[o], be = beta[o];

    const f16* src = yh + ((size_t)b * COUT + o) * NL;
    float*     dst = y  + ((size_t)b * COUT + o) * NL;
    #pragma unroll
    for (int it = 0; it < 4; ++it) {
        const int base = it * 2048 + tid * 8;
        f16x8 v = *(const f16x8*)(src + base);
        float4 o1, o2;
        o1.x = fmaxf(fmaf(g, ((float)v[0] - mu) * rs, be), 0.0f);
        o1.y = fmaxf(fmaf(g, ((float)v[1] - mu) * rs, be), 0.0f);
        o1.z = fmaxf(fmaf(g, ((float)v[2] - mu) * rs, be), 0.0f);
        o1.w = fmaxf(fmaf(g, ((float)v[3] - mu) * rs, be), 0.0f);
        o2.x = fmaxf(fmaf(g, ((float)v[4] - mu) * rs, be), 0.0f);
        o2.y = fmaxf(fmaf(g, ((float)v[5] - mu) * rs, be), 0.0f);
        o2.z = fmaxf(fmaf(g, ((float)v[6] - mu) * rs, be), 0.0f);
        o2.w = fmaxf(fmaf(g, ((float)v[7] - mu) * rs, be), 0.0f);
        *(float4*)(dst + base)     = o1;
        *(float4*)(dst + base + 4) = o2;
    }
}

// ---------------------------------------------------------------------------
extern "C" void kernel_launch(void* const* d_in, const int* in_sizes, int n_in,
                              void* d_out, int out_size, void* d_ws, size_t ws_size,
                              hipStream_t stream)
{
    const float* xyz_low   = (const float*)d_in[0];
    const float* xyz_high  = (const float*)d_in[1];
    const float* feat_low  = (const float*)d_in[2];
    const float* feat_high = (const float*)d_in[3];
    const float* Wm        = (const float*)d_in[4];
    const float* bias      = (const float*)d_in[5];
    const float* gamma     = (const float*)d_in[6];
    const float* beta      = (const float*)d_in[7];
    float* y = (float*)d_out;

    float* ps   = (float*)d_ws;                        // 256*512 f32
    float* psq  = ps + (size_t)COUT * 512;             // 256*512 f32
    int*   idxG = (int*)(psq + (size_t)COUT * 512);    // 512*192 int
    float* wG   = (float*)(idxG + 512 * 192);          // 512*192 f32
    f16*   Wh   = (f16*)(wG + 512 * 192);              // 256*384 f16
    f16*   fhT  = Wh + (size_t)COUT * CIN;             // 4*2048*256 f16 (4.2MB)
    f16*   yh   = fhT + (size_t)B_ * NH * CH;          // 4*256*8192 f16 (16.8MB)

    knn_prep_kernel<<<1408, 256, 0, stream>>>(
        xyz_low, xyz_high, feat_high, Wm, fhT, Wh, idxG, wG);
    gemm_kernel<<<512, 256, 0, stream>>>(
        feat_low, fhT, Wh, bias, idxG, wG, yh, ps, psq);
    stats_apply_kernel<<<dim3(COUT, B_), 256, 0, stream>>>(
        ps, psq, yh, gamma, beta, y);
}